// Round 13
// baseline (397.009 us; speedup 1.0000x reference)
//
#include <hip/hip_runtime.h>
#include <math.h>

// DecoderBlock: B=8, T=1024, D=768, H=12, HD=64
// Lessons:
//  R3: global_load_lds stale-data hazard -> VGPR staging only.
//  R7/R9/R14: register prefetch across MFMA section ALWAYS spills.
//  R16: uint4-array staging re-triggers spill. NAMED SCALARS ONLY.
//  R4: XOR-swizzle [row][chunk^row&7]: 0 bank conflicts.
//  R11/R13: 32-key softmax groups + paired q-tiles. R12/R15 FAILED.
//  R17/R20: BM=64 everywhere: occupancy > tile size for 2-barrier loop.
//  R18 NEUTRAL: attn XOR swizzle (kept). R19 NEUTRAL/NEG: raw barriers (reverted).
//  R21 NEUTRAL: fused prelude (kept: fewer dispatches). Launch gaps not the lever.
//  R22 (this round): BN=256 for the big-N GEMMs (QKV N=2304, FC N=3072):
//      32 MFMAs per barrier-pair (vs 16) at 10 staged uint4 (vs 6) -- halves
//      barrier/staging cost per FLOP with NO cross-barrier register lifetime.
//      LDS 40KB, acc[2][8], named scalars bv0..bv7. proj/CP stay BN=128
//      (BN=256 would grid-starve N=768).

typedef unsigned short ushort_t;
typedef __attribute__((ext_vector_type(8))) __bf16 bf16x8;
typedef __attribute__((ext_vector_type(4))) __bf16 bf16x4;
typedef __attribute__((ext_vector_type(4))) float floatx4;

__device__ __forceinline__ float bf2f(ushort_t u) {
  unsigned int x = ((unsigned int)u) << 16;
  return __builtin_bit_cast(float, x);
}
__device__ __forceinline__ ushort_t f2bf(float f) {
  unsigned int x = __builtin_bit_cast(unsigned int, f);
  unsigned int r = (x + 0x7FFFu + ((x >> 16) & 1u)) >> 16;
  return (ushort_t)r;
}

// ---------------- fused prelude: LN1 + all 4 weight repacks (independent work) ----------
__device__ __forceinline__ void transpose_w_body(const float* __restrict__ in,
                                                 ushort_t* __restrict__ out,
                                                 int R, int C, int bx, int by,
                                                 ushort_t* tl) {
  int tid = threadIdx.x;
  int c0 = bx * 64, r0 = by * 64;
  #pragma unroll
  for (int i = 0; i < 16; ++i) {
    int idx = tid + i * 256;
    int r = idx >> 6, c = idx & 63;
    tl[c * 65 + r] = f2bf(in[(size_t)(r0 + r) * C + c0 + c]);
  }
  __syncthreads();
  #pragma unroll
  for (int i = 0; i < 16; ++i) {
    int idx = tid + i * 256;
    int c = idx >> 6, r = idx & 63;
    out[(size_t)(c0 + c) * R + r0 + r] = tl[c * 65 + r];
  }
}

__global__ void __launch_bounds__(256) fused_pre(
    const float* __restrict__ x, const float* __restrict__ g1,
    const float* __restrict__ be1, ushort_t* __restrict__ hbuf,
    const float* __restrict__ wq, const float* __restrict__ wk,
    const float* __restrict__ wv, ushort_t* __restrict__ wqkvT,
    const float* __restrict__ w_proj, ushort_t* __restrict__ wprojT,
    const float* __restrict__ w_fc, ushort_t* __restrict__ wfcT,
    const float* __restrict__ w_cp, ushort_t* __restrict__ wcpT) {
  __shared__ ushort_t tl[64 * 65];
  __shared__ float ws1[4], ws2[4];
  int bid = blockIdx.x;
  int tid = threadIdx.x;
  if (bid < 8192) {
    const float* xr = x + (size_t)bid * 768;
    float v0 = xr[tid], v1 = xr[tid + 256], v2 = xr[tid + 512];
    float s = v0 + v1 + v2;
    float s2 = v0 * v0 + v1 * v1 + v2 * v2;
    #pragma unroll
    for (int off = 32; off; off >>= 1) {
      s += __shfl_xor(s, off, 64);
      s2 += __shfl_xor(s2, off, 64);
    }
    int w = tid >> 6;
    if ((tid & 63) == 0) { ws1[w] = s; ws2[w] = s2; }
    __syncthreads();
    float S = ws1[0] + ws1[1] + ws1[2] + ws1[3];
    float S2 = ws2[0] + ws2[1] + ws2[2] + ws2[3];
    float mean = S * (1.0f / 768.0f);
    float var = S2 * (1.0f / 768.0f) - mean * mean;
    float rstd = rsqrtf(var + 1e-5f);
    ushort_t* orow = hbuf + (size_t)bid * 768;
    orow[tid]       = f2bf((v0 - mean) * rstd * g1[tid]       + be1[tid]);
    orow[tid + 256] = f2bf((v1 - mean) * rstd * g1[tid + 256] + be1[tid + 256]);
    orow[tid + 512] = f2bf((v2 - mean) * rstd * g1[tid + 512] + be1[tid + 512]);
  } else if (bid < 8624) {
    int t = bid - 8192;
    int bx = t % 12, by = t / 12;
    int s = by / 12, h = by % 12;
    const float* w = ((s == 0) ? wq : (s == 1) ? wk : wv) + (size_t)h * 768 * 64;
    int d0 = bx * 64;
    #pragma unroll
    for (int i = 0; i < 16; ++i) {
      int idx = tid + i * 256;
      int r = idx >> 6, c = idx & 63;   // r: d offset, c: hd
      tl[c * 65 + r] = f2bf(w[(size_t)(d0 + r) * 64 + c]);
    }
    __syncthreads();
    ushort_t* ob = wqkvT + (size_t)(s * 768 + h * 64) * 768;
    #pragma unroll
    for (int i = 0; i < 16; ++i) {
      int idx = tid + i * 256;
      int c = idx >> 6, r = idx & 63;   // c: hd, r: d offset
      ob[(size_t)c * 768 + d0 + r] = tl[c * 65 + r];
    }
  } else if (bid < 8768) {
    int t = bid - 8624;
    transpose_w_body(w_proj, wprojT, 768, 768, t % 12, t / 12, tl);
  } else if (bid < 9344) {
    int t = bid - 8768;
    transpose_w_body(w_fc, wfcT, 768, 3072, t % 48, t / 48, tl);
  } else {
    int t = bid - 9344;
    transpose_w_body(w_cp, wcpT, 3072, 768, t % 12, t / 12, tl);
  }
}

// ---------------- layernorm: fp32 row [768] -> bf16 row (LN2) ----------------
__global__ void __launch_bounds__(256) ln_kernel(const float* __restrict__ x,
                                                 const float* __restrict__ g,
                                                 const float* __restrict__ b,
                                                 ushort_t* __restrict__ out) {
  int row = blockIdx.x;
  int tid = threadIdx.x;
  const float* xr = x + (size_t)row * 768;
  float v0 = xr[tid], v1 = xr[tid + 256], v2 = xr[tid + 512];
  float s = v0 + v1 + v2;
  float s2 = v0 * v0 + v1 * v1 + v2 * v2;
  #pragma unroll
  for (int off = 32; off; off >>= 1) {
    s += __shfl_xor(s, off, 64);
    s2 += __shfl_xor(s2, off, 64);
  }
  __shared__ float ws1[4], ws2[4];
  int w = tid >> 6;
  if ((tid & 63) == 0) { ws1[w] = s; ws2[w] = s2; }
  __syncthreads();
  float S = ws1[0] + ws1[1] + ws1[2] + ws1[3];
  float S2 = ws2[0] + ws2[1] + ws2[2] + ws2[3];
  float mean = S * (1.0f / 768.0f);
  float var = S2 * (1.0f / 768.0f) - mean * mean;
  float rstd = rsqrtf(var + 1e-5f);
  ushort_t* orow = out + (size_t)row * 768;
  orow[tid]       = f2bf((v0 - mean) * rstd * g[tid]       + b[tid]);
  orow[tid + 256] = f2bf((v1 - mean) * rstd * g[tid + 256] + b[tid + 256]);
  orow[tid + 512] = f2bf((v2 - mean) * rstd * g[tid + 512] + b[tid + 512]);
}

enum { EPI_QKV = 0, EPI_RES = 1, EPI_FC = 2 };

// ---------------- 64x256 MFMA GEMM for big-N (QKV/FC): 32 MFMA per barrier-pair --------
template <int EPI>
__global__ void __launch_bounds__(256) gemm64w(
    const ushort_t* __restrict__ A, const ushort_t* __restrict__ Bt,
    int M, int N, int K,
    const float* __restrict__ b0, const float* __restrict__ b1, const float* __restrict__ b2,
    ushort_t* __restrict__ ob0, ushort_t* __restrict__ ob1, ushort_t* __restrict__ ob2) {
  __shared__ __align__(16) ushort_t la[64 * 64];     // 8 KB
  __shared__ __align__(16) ushort_t lb[256 * 64];    // 32 KB
  int tid = threadIdx.x;
  int lane = tid & 63;
  int w = tid >> 6;
  int wr = w >> 1, wc = w & 1;
  int lm = lane & 15, q = lane >> 4;
  int m0 = blockIdx.x * 64, n0 = blockIdx.y * 256;

  const ushort_t* Ab = A + (size_t)m0 * K;
  const ushort_t* Bb = Bt + (size_t)n0 * K;

  floatx4 acc[2][8];
  #pragma unroll
  for (int i = 0; i < 2; ++i)
    #pragma unroll
    for (int j = 0; j < 8; ++j) acc[i][j] = (floatx4){0.f, 0.f, 0.f, 0.f};

  int srow = tid >> 3;            // 0..31
  int sch  = tid & 7;             // chunk 0..7
  for (int k0 = 0; k0 < K; k0 += 64) {
    uint4 av0 = *reinterpret_cast<const uint4*>(Ab + (size_t)srow * K + k0 + sch * 8);
    uint4 av1 = *reinterpret_cast<const uint4*>(Ab + (size_t)(srow + 32) * K + k0 + sch * 8);
    uint4 bv0 = *reinterpret_cast<const uint4*>(Bb + (size_t)srow * K + k0 + sch * 8);
    uint4 bv1 = *reinterpret_cast<const uint4*>(Bb + (size_t)(srow + 32) * K + k0 + sch * 8);
    uint4 bv2 = *reinterpret_cast<const uint4*>(Bb + (size_t)(srow + 64) * K + k0 + sch * 8);
    uint4 bv3 = *reinterpret_cast<const uint4*>(Bb + (size_t)(srow + 96) * K + k0 + sch * 8);
    uint4 bv4 = *reinterpret_cast<const uint4*>(Bb + (size_t)(srow + 128) * K + k0 + sch * 8);
    uint4 bv5 = *reinterpret_cast<const uint4*>(Bb + (size_t)(srow + 160) * K + k0 + sch * 8);
    uint4 bv6 = *reinterpret_cast<const uint4*>(Bb + (size_t)(srow + 192) * K + k0 + sch * 8);
    uint4 bv7 = *reinterpret_cast<const uint4*>(Bb + (size_t)(srow + 224) * K + k0 + sch * 8);
    __syncthreads();   // previous tile's LDS reads all consumed
    *reinterpret_cast<uint4*>(&la[srow * 64 + ((sch ^ (srow & 7)) << 3)]) = av0;
    *reinterpret_cast<uint4*>(&la[(srow + 32) * 64 + ((sch ^ (srow & 7)) << 3)]) = av1;
    *reinterpret_cast<uint4*>(&lb[srow * 64 + ((sch ^ (srow & 7)) << 3)]) = bv0;
    *reinterpret_cast<uint4*>(&lb[(srow + 32) * 64 + ((sch ^ (srow & 7)) << 3)]) = bv1;
    *reinterpret_cast<uint4*>(&lb[(srow + 64) * 64 + ((sch ^ (srow & 7)) << 3)]) = bv2;
    *reinterpret_cast<uint4*>(&lb[(srow + 96) * 64 + ((sch ^ (srow & 7)) << 3)]) = bv3;
    *reinterpret_cast<uint4*>(&lb[(srow + 128) * 64 + ((sch ^ (srow & 7)) << 3)]) = bv4;
    *reinterpret_cast<uint4*>(&lb[(srow + 160) * 64 + ((sch ^ (srow & 7)) << 3)]) = bv5;
    *reinterpret_cast<uint4*>(&lb[(srow + 192) * 64 + ((sch ^ (srow & 7)) << 3)]) = bv6;
    *reinterpret_cast<uint4*>(&lb[(srow + 224) * 64 + ((sch ^ (srow & 7)) << 3)]) = bv7;
    __syncthreads();
    #pragma unroll
    for (int kk = 0; kk < 64; kk += 32) {
      int ch = (kk >> 3) + q;
      bf16x8 af[2], bfr[8];
      #pragma unroll
      for (int i = 0; i < 2; ++i) {
        int ra = wr * 32 + i * 16 + lm;
        af[i]  = *reinterpret_cast<const bf16x8*>(&la[ra * 64 + ((ch ^ (ra & 7)) << 3)]);
      }
      #pragma unroll
      for (int j = 0; j < 8; ++j) {
        int rb = wc * 128 + j * 16 + lm;
        bfr[j] = *reinterpret_cast<const bf16x8*>(&lb[rb * 64 + ((ch ^ (rb & 7)) << 3)]);
      }
      #pragma unroll
      for (int i = 0; i < 2; ++i)
        #pragma unroll
        for (int j = 0; j < 8; ++j)
          acc[i][j] = __builtin_amdgcn_mfma_f32_16x16x32_bf16(af[i], bfr[j], acc[i][j], 0, 0, 0);
    }
  }

  // epilogue; C/D layout: row(m)=quad*4+reg, col(n)=lane&15  [verified m89/m91]
  #pragma unroll
  for (int i = 0; i < 2; ++i) {
    #pragma unroll
    for (int j = 0; j < 8; ++j) {
      #pragma unroll
      for (int r = 0; r < 4; ++r) {
        float vacc = acc[i][j][r];
        int mm = m0 + wr * 32 + i * 16 + q * 4 + r;
        int nn = n0 + wc * 128 + j * 16 + lm;
        if constexpr (EPI == EPI_QKV) {
          int sel = nn / 768;            // 0:q 1:k 2:v (256 | 768 boundaries align)
          int nq = nn - sel * 768;       // h*64+hd
          const float* bp = (sel == 0) ? b0 : (sel == 1) ? b1 : b2;
          ushort_t* dst = (sel == 0) ? ob0 : (sel == 1) ? ob1 : ob2;
          int bh = (mm >> 10) * 12 + (nq >> 6);
          size_t o = (size_t)bh * 65536 + (size_t)(mm & 1023) * 64 + (nq & 63);
          dst[o] = f2bf(vacc + bp[nq]);
        } else {  // EPI_FC: gelu(acc+bias) -> bf16 [M,3072]
          float u = vacc + b0[nn];
          float inner = 0.7978845608028654f * (u + 0.044715f * u * u * u);
          float e = __builtin_amdgcn_exp2f(inner * 2.885390081777927f);  // 2*log2(e)
          float gl = u - u / (e + 1.0f);   // e=inf -> u; e=0 -> 0 (NaN-safe)
          ob0[(size_t)mm * 3072 + nn] = f2bf(gl);
        }
      }
    }
  }
}

// ---------------- 64x128 MFMA GEMM for proj/CP (R20 proven, EPI_RES) ----------------
__global__ void __launch_bounds__(256) gemm64n(
    const ushort_t* __restrict__ A, const ushort_t* __restrict__ Bt,
    int M, int N, int K,
    const float* __restrict__ b0,
    const float* __restrict__ resid,
    float* __restrict__ of) {
  __shared__ __align__(16) ushort_t la[64 * 64];
  __shared__ __align__(16) ushort_t lb[128 * 64];
  int tid = threadIdx.x;
  int lane = tid & 63;
  int w = tid >> 6;
  int wr = w >> 1, wc = w & 1;
  int lm = lane & 15, q = lane >> 4;
  int m0 = blockIdx.x * 64, n0 = blockIdx.y * 128;

  const ushort_t* Ab = A + (size_t)m0 * K;
  const ushort_t* Bb = Bt + (size_t)n0 * K;

  floatx4 acc[2][4];
  #pragma unroll
  for (int i = 0; i < 2; ++i)
    #pragma unroll
    for (int j = 0; j < 4; ++j) acc[i][j] = (floatx4){0.f, 0.f, 0.f, 0.f};

  int srow = tid >> 3;            // 0..31
  int sch  = tid & 7;             // chunk 0..7
  for (int k0 = 0; k0 < K; k0 += 64) {
    uint4 av0 = *reinterpret_cast<const uint4*>(Ab + (size_t)srow * K + k0 + sch * 8);
    uint4 av1 = *reinterpret_cast<const uint4*>(Ab + (size_t)(srow + 32) * K + k0 + sch * 8);
    uint4 bv0 = *reinterpret_cast<const uint4*>(Bb + (size_t)srow * K + k0 + sch * 8);
    uint4 bv1 = *reinterpret_cast<const uint4*>(Bb + (size_t)(srow + 32) * K + k0 + sch * 8);
    uint4 bv2 = *reinterpret_cast<const uint4*>(Bb + (size_t)(srow + 64) * K + k0 + sch * 8);
    uint4 bv3 = *reinterpret_cast<const uint4*>(Bb + (size_t)(srow + 96) * K + k0 + sch * 8);
    __syncthreads();   // previous tile's LDS reads all consumed
    *reinterpret_cast<uint4*>(&la[srow * 64 + ((sch ^ (srow & 7)) << 3)]) = av0;
    *reinterpret_cast<uint4*>(&la[(srow + 32) * 64 + ((sch ^ (srow & 7)) << 3)]) = av1;
    *reinterpret_cast<uint4*>(&lb[srow * 64 + ((sch ^ (srow & 7)) << 3)]) = bv0;
    *reinterpret_cast<uint4*>(&lb[(srow + 32) * 64 + ((sch ^ (srow & 7)) << 3)]) = bv1;
    *reinterpret_cast<uint4*>(&lb[(srow + 64) * 64 + ((sch ^ (srow & 7)) << 3)]) = bv2;
    *reinterpret_cast<uint4*>(&lb[(srow + 96) * 64 + ((sch ^ (srow & 7)) << 3)]) = bv3;
    __syncthreads();
    #pragma unroll
    for (int kk = 0; kk < 64; kk += 32) {
      int ch = (kk >> 3) + q;
      bf16x8 af[2], bfr[4];
      #pragma unroll
      for (int i = 0; i < 2; ++i) {
        int ra = wr * 32 + i * 16 + lm;
        af[i]  = *reinterpret_cast<const bf16x8*>(&la[ra * 64 + ((ch ^ (ra & 7)) << 3)]);
      }
      #pragma unroll
      for (int j = 0; j < 4; ++j) {
        int rb = wc * 64 + j * 16 + lm;
        bfr[j] = *reinterpret_cast<const bf16x8*>(&lb[rb * 64 + ((ch ^ (rb & 7)) << 3)]);
      }
      #pragma unroll
      for (int i = 0; i < 2; ++i)
        #pragma unroll
        for (int j = 0; j < 4; ++j)
          acc[i][j] = __builtin_amdgcn_mfma_f32_16x16x32_bf16(af[i], bfr[j], acc[i][j], 0, 0, 0);
    }
  }

  // epilogue (EPI_RES): C/D layout row(m)=quad*4+reg, col(n)=lane&15
  #pragma unroll
  for (int i = 0; i < 2; ++i) {
    #pragma unroll
    for (int j = 0; j < 4; ++j) {
      #pragma unroll
      for (int r = 0; r < 4; ++r) {
        float vacc = acc[i][j][r];
        int mm = m0 + wr * 32 + i * 16 + q * 4 + r;
        int nn = n0 + wc * 64 + j * 16 + lm;
        size_t o = (size_t)mm * 768 + nn;
        of[o] = vacc + b0[nn] + resid[o];
      }
    }
  }
}

// ---------------- V transpose: [bh][1024][64] -> [bh][64][1024] (bf16) ----------------
__global__ void __launch_bounds__(256) transpose_v(const ushort_t* __restrict__ vb,
                                                   ushort_t* __restrict__ vt) {
  __shared__ ushort_t tl[64 * 72];
  int kt = blockIdx.x, bh = blockIdx.y;
  size_t base = (size_t)bh * 65536;
  int tid = threadIdx.x;
  #pragma unroll
  for (int i = 0; i < 2; ++i) {
    int r = (tid >> 3) + i * 32;     // local key row
    int cb = (tid & 7) * 8;          // dim chunk
    *reinterpret_cast<uint4*>(&tl[r * 72 + cb]) =
        *reinterpret_cast<const uint4*>(vb + base + (size_t)(kt * 64 + r) * 64 + cb);
  }
  __syncthreads();
  #pragma unroll
  for (int i = 0; i < 2; ++i) {
    int dim = (tid >> 3) + i * 32;
    int kb8 = (tid & 7) * 8;
    ushort_t tmp[8];
    #pragma unroll
    for (int j = 0; j < 8; ++j) tmp[j] = tl[(kb8 + j) * 72 + dim];
    *reinterpret_cast<uint4*>(vt + base + (size_t)dim * 1024 + kt * 64 + kb8) =
        *reinterpret_cast<uint4*>(tmp);
  }
}

// ---------------- MFMA flash attention (paired q-tiles, XOR-swizzled LDS) ----------------
__global__ void __launch_bounds__(256) attn_mfma(const ushort_t* __restrict__ qb,
                                                 const ushort_t* __restrict__ kb,
                                                 const ushort_t* __restrict__ vtb,
                                                 ushort_t* __restrict__ yb) {
  __shared__ __align__(16) ushort_t kl[64 * 64];   // K tile [key][dim], swizzled
  __shared__ __align__(16) ushort_t vtl[64 * 64];  // V^T tile [dim][key], swizzled
  int p = blockIdx.x;                              // 0..7
  int bh = blockIdx.y;
  int tid = threadIdx.x, lane = tid & 63, w = tid >> 6;
  int col = lane & 15, quad = lane >> 4;
  size_t base = (size_t)bh * 65536;
  int b = bh / 12, h = bh - b * 12;
  const float sscale = 0.125f * 1.4426950408889634f;  // 1/sqrt(64) * log2(e)

  for (int phase = 0; phase < 2; ++phase) {
    int qt = (phase == 0) ? (15 - p) : p;          // heavy first
    int qw0 = qt * 64 + w * 16;                    // wave's first query
    int qg = qw0 + col;

    bf16x8 qf0 = *reinterpret_cast<const bf16x8*>(qb + base + (size_t)(qw0 + col) * 64 + quad * 8);
    bf16x8 qf1 = *reinterpret_cast<const bf16x8*>(qb + base + (size_t)(qw0 + col) * 64 + 32 + quad * 8);

    floatx4 O[4];
    #pragma unroll
    for (int ss = 0; ss < 4; ++ss) O[ss] = (floatx4){0.f, 0.f, 0.f, 0.f};
    float m = -INFINITY, l = 0.f;

    for (int kt0 = 0; kt0 <= qt * 64; kt0 += 64) {
      __syncthreads();   // previous tile's (or phase's) LDS reads all consumed
      {
        int r0 = tid >> 3;           // 0..31
        int cb = tid & 7;            // chunk 0..7
        int sw = (cb ^ (r0 & 7)) << 3;
        *reinterpret_cast<uint4*>(&kl[r0 * 64 + sw]) =
            *reinterpret_cast<const uint4*>(kb + base + (size_t)(kt0 + r0) * 64 + cb * 8);
        *reinterpret_cast<uint4*>(&vtl[r0 * 64 + sw]) =
            *reinterpret_cast<const uint4*>(vtb + base + (size_t)r0 * 1024 + kt0 + cb * 8);
        int r1 = r0 + 32;            // (r1&7)==(r0&7), same swizzle slot
        *reinterpret_cast<uint4*>(&kl[r1 * 64 + sw]) =
            *reinterpret_cast<const uint4*>(kb + base + (size_t)(kt0 + r1) * 64 + cb * 8);
        *reinterpret_cast<uint4*>(&vtl[r1 * 64 + sw]) =
            *reinterpret_cast<const uint4*>(vtb + base + (size_t)r1 * 1024 + kt0 + cb * 8);
      }
      __syncthreads();
      int nk = qw0 + 16 - kt0;           // keys this wave needs in this tile
      if (nk > 64) nk = 64;
      int ng = (nk + 31) >> 5;           // 32-key groups
      for (int g = 0; g < ng; ++g) {
        int ksA = kt0 + g * 32;
        int ksB = ksA + 16;
        int rowA = g * 32 + col;          // key row for subtile A
        int rxa = rowA & 7;               // == (rowA+16)&7
        int sa = rowA * 64;
        int sb = sa + 16 * 64;
        bf16x8 kfA0 = *reinterpret_cast<const bf16x8*>(&kl[sa + ((quad ^ rxa) << 3)]);
        bf16x8 kfA1 = *reinterpret_cast<const bf16x8*>(&kl[sa + (((4 + quad) ^ rxa) << 3)]);
        bf16x8 kfB0 = *reinterpret_cast<const bf16x8*>(&kl[sb + ((quad ^ rxa) << 3)]);
        bf16x8 kfB1 = *reinterpret_cast<const bf16x8*>(&kl[sb + (((4 + quad) ^ rxa) << 3)]);
        floatx4 saA = (floatx4){0.f, 0.f, 0.f, 0.f};
        floatx4 saB = (floatx4){0.f, 0.f, 0.f, 0.f};
        __builtin_amdgcn_s_setprio(1);
        saA = __builtin_amdgcn_mfma_f32_16x16x32_bf16(kfA0, qf0, saA, 0, 0, 0);
        saA = __builtin_amdgcn_mfma_f32_16x16x32_bf16(kfA1, qf1, saA, 0, 0, 0);
        saB = __builtin_amdgcn_mfma_f32_16x16x32_bf16(kfB0, qf0, saB, 0, 0, 0);
        saB = __builtin_amdgcn_mfma_f32_16x16x32_bf16(kfB1, qf1, saB, 0, 0, 0);
        __builtin_amdgcn_s_setprio(0);
        float s0 = saA[0] * sscale, s1 = saA[1] * sscale;
        float s2 = saA[2] * sscale, s3 = saA[3] * sscale;
        float s4 = saB[0] * sscale, s5 = saB[1] * sscale;
        float s6 = saB[2] * sscale, s7 = saB[3] * sscale;
        if (ksA + 15 > qw0) {   // wave-uniform: subtile A touches/crosses diagonal
          int keyb = ksA + quad * 4;
          if (keyb + 0 > qg) s0 = -3.0e38f;
          if (keyb + 1 > qg) s1 = -3.0e38f;
          if (keyb + 2 > qg) s2 = -3.0e38f;
          if (keyb + 3 > qg) s3 = -3.0e38f;
        }
        if (ksB + 15 > qw0) {   // wave-uniform: subtile B (also handles odd tail)
          int keyb = ksB + quad * 4;
          if (keyb + 0 > qg) s4 = -3.0e38f;
          if (keyb + 1 > qg) s5 = -3.0e38f;
          if (keyb + 2 > qg) s6 = -3.0e38f;
          if (keyb + 3 > qg) s7 = -3.0e38f;
        }
        float mloc = fmaxf(fmaxf(fmaxf(s0, s1), fmaxf(s2, s3)),
                           fmaxf(fmaxf(s4, s5), fmaxf(s6, s7)));
        mloc = fmaxf(mloc, __shfl_xor(mloc, 16, 64));
        mloc = fmaxf(mloc, __shfl_xor(mloc, 32, 64));
        float mnew = fmaxf(m, mloc);
        float c = __builtin_amdgcn_exp2f(m - mnew);
        float p0 = __builtin_amdgcn_exp2f(s0 - mnew);
        float p1 = __builtin_amdgcn_exp2f(s1 - mnew);
        float p2 = __builtin_amdgcn_exp2f(s2 - mnew);
        float p3 = __builtin_amdgcn_exp2f(s3 - mnew);
        float p4 = __builtin_amdgcn_exp2f(s4 - mnew);
        float p5 = __builtin_amdgcn_exp2f(s5 - mnew);
        float p6 = __builtin_amdgcn_exp2f(s6 - mnew);
        float p7 = __builtin_amdgcn_exp2f(s7 - mnew);
        float ll = ((p0 + p1) + (p2 + p3)) + ((p4 + p5) + (p6 + p7));
        ll += __shfl_xor(ll, 16, 64);
        ll += __shfl_xor(ll, 32, 64);
        l = l * c + ll;
        m = mnew;
        float c0 = __shfl(c, quad * 4 + 0, 64);
        float c1 = __shfl(c, quad * 4 + 1, 64);
        float c2 = __shfl(c, quad * 4 + 2, 64);
        float c3 = __shfl(c, quad * 4 + 3, 64);
        bf16x8 pf = {(__bf16)p0, (__bf16)p1, (__bf16)p2, (__bf16)p3,
                     (__bf16)p4, (__bf16)p5, (__bf16)p6, (__bf16)p7};
        __builtin_amdgcn_s_setprio(1);
        #pragma unroll
        for (int ss = 0; ss < 4; ++ss) {
          O[ss][0] *= c0; O[ss][1] *= c1; O[ss][2] *= c2; O[ss][3] *= c3;
          int vd = ss * 16 + col;
          int vbase = vd * 64;
          int vx = vd & 7;
          int ca = g * 4 + (quad >> 1);
          int ia = (quad & 1) * 4;
          bf16x4 va = *reinterpret_cast<const bf16x4*>(&vtl[vbase + ((ca ^ vx) << 3) + ia]);
          bf16x4 vb = *reinterpret_cast<const bf16x4*>(&vtl[vbase + (((ca + 2) ^ vx) << 3) + ia]);
          bf16x8 vf = {va[0], va[1], va[2], va[3], vb[0], vb[1], vb[2], vb[3]};
          O[ss] = __builtin_amdgcn_mfma_f32_16x16x32_bf16(pf, vf, O[ss], 0, 0, 0);
        }
        __builtin_amdgcn_s_setprio(0);
      }
    }

    float linv = 1.0f / l;
    float l0 = __shfl(linv, quad * 4 + 0, 64);
    float l1 = __shfl(linv, quad * 4 + 1, 64);
    float l2 = __shfl(linv, quad * 4 + 2, 64);
    float l3 = __shfl(linv, quad * 4 + 3, 64);
    #pragma unroll
    for (int ss = 0; ss < 4; ++ss) {
      float lr[4] = {l0, l1, l2, l3};
      #pragma unroll
      for (int r = 0; r < 4; ++r) {
        int t = qw0 + quad * 4 + r;
        yb[((size_t)(b * 1024 + t)) * 768 + h * 64 + ss * 16 + col] = f2bf(O[ss][r] * lr[r]);
      }
    }
  }
}

// ---------------- launch ----------------
extern "C" void kernel_launch(void* const* d_in, const int* in_sizes, int n_in,
                              void* d_out, int out_size, void* d_ws, size_t ws_size,
                              hipStream_t stream) {
  const float* x      = (const float*)d_in[0];
  const float* wq     = (const float*)d_in[1];
  const float* bq     = (const float*)d_in[2];
  const float* wk     = (const float*)d_in[3];
  const float* bk     = (const float*)d_in[4];
  const float* wv     = (const float*)d_in[5];
  const float* bv     = (const float*)d_in[6];
  const float* w_proj = (const float*)d_in[7];
  const float* b_proj = (const float*)d_in[8];
  const float* g1     = (const float*)d_in[9];
  const float* be1    = (const float*)d_in[10];
  const float* g2     = (const float*)d_in[11];
  const float* be2    = (const float*)d_in[12];
  const float* w_fc   = (const float*)d_in[13];
  const float* b_fc   = (const float*)d_in[14];
  const float* w_cp   = (const float*)d_in[15];
  const float* b_cp   = (const float*)d_in[16];
  float* out = (float*)d_out;

  char* ws = (char*)d_ws;
  size_t off = 0;
  auto alloc = [&](size_t bytes) -> char* {
    char* p = ws + off;
    off += (bytes + 255) & ~(size_t)255;
    return p;
  };
  const size_t MD = 8192ull * 768;  // B*T*D elements
  ushort_t* wqkvT  = (ushort_t*)alloc(2304ull * 768 * 2);   // [N=2304][K=768]
  ushort_t* wprojT = (ushort_t*)alloc(768ull * 768 * 2);    // [N=768][K=768]
  ushort_t* wfcT   = (ushort_t*)alloc(3072ull * 768 * 2);   // [N=3072][K=768]
  ushort_t* wcpT   = (ushort_t*)alloc(768ull * 3072 * 2);   // [N=768][K=3072]
  ushort_t* hbuf   = (ushort_t*)alloc(MD * 2);
  ushort_t* qbuf   = (ushort_t*)alloc(MD * 2);
  ushort_t* kbuf   = (ushort_t*)alloc(MD * 2);
  ushort_t* vbuf   = (ushort_t*)alloc(MD * 2);
  ushort_t* ybuf   = (ushort_t*)alloc(MD * 2);
  float*    x1     = (float*)alloc(MD * 4);
  ushort_t* h2buf  = (ushort_t*)alloc(MD * 2);
  // aliases (lifetimes disjoint): vtbuf reuses hbuf (dead after QKV GEMM);
  // fcbuf reuses qbuf..ybuf (48 MB exactly, dead after proj GEMM)
  ushort_t* vtbuf  = hbuf;
  ushort_t* fcbuf  = qbuf;

  // fused prelude: LN1 + all 4 weight repacks (independent; one dispatch)
  fused_pre<<<9920, 256, 0, stream>>>(x, g1, be1, hbuf, wq, wk, wv, wqkvT,
                                      w_proj, wprojT, w_fc, wfcT, w_cp, wcpT);
  // QKV projection: 64x256 tiles, grid (128, 9)
  gemm64w<EPI_QKV><<<dim3(128, 9), 256, 0, stream>>>(
      hbuf, wqkvT, 8192, 2304, 768, bq, bk, bv, qbuf, kbuf, vbuf);
  // V -> V^T  (hbuf dead, reused as vtbuf)
  transpose_v<<<dim3(16, 96), 256, 0, stream>>>(vbuf, vtbuf);
  // causal MFMA flash attention (paired q-tiles: grid (8, 96))
  attn_mfma<<<dim3(8, 96), 256, 0, stream>>>(qbuf, kbuf, vtbuf, ybuf);
  // out-proj + bias + residual(x) -> x1 fp32: 64x128 tiles, 768 blocks
  gemm64n<<<dim3(128, 6), 256, 0, stream>>>(
      ybuf, wprojT, 8192, 768, 768, b_proj, x, x1);
  // LN2
  ln_kernel<<<8192, 256, 0, stream>>>(x1, g2, be2, h2buf);
  // FC + gelu -> bf16: 64x256 tiles, grid (128, 12)
  gemm64w<EPI_FC><<<dim3(128, 12), 256, 0, stream>>>(
      h2buf, wfcT, 8192, 3072, 768, b_fc, nullptr, nullptr, fcbuf, nullptr, nullptr);
  // CP + bias + residual(x1) -> out fp32: 64x128 tiles, 768 blocks
  gemm64n<<<dim3(128, 6), 256, 0, stream>>>(
      fcbuf, wcpT, 8192, 768, 3072, b_cp, x1, out);
}

// Round 14
// 381.125 us; speedup vs baseline: 1.0417x; 1.0417x over previous
//
#include <hip/hip_runtime.h>
#include <math.h>

// DecoderBlock: B=8, T=1024, D=768, H=12, HD=64
// FINAL configuration = R20/R21 proven best (388.5 us).
// Lessons ledger:
//  R3: global_load_lds stale-data hazard -> VGPR staging only.
//  R7/R9/R14: register prefetch across MFMA section ALWAYS spills.
//  R16: uint4-array staging re-triggers spill. NAMED SCALARS ONLY.
//  R4: XOR-swizzle [row][chunk^row&7]: 0 bank conflicts.
//  R11/R13: 32-key softmax groups + paired q-tiles. R12/R15 FAILED.
//  R17/R20: BM=64/BN=128 everywhere: occupancy > tile size (36% occ, VGPR 60).
//  R18 NEUTRAL (kept): attn XOR swizzle, less LDS.
//  R19 NEUTRAL: raw barriers. R21 NEUTRAL (kept): fused prelude.
//  R22 FAILED: BN=256 dropped occupancy 36->19%, FC 67->77us. Tile space
//      exhausted: {64,128}x{128,256} all measured, 64x128 optimal.
//  Structural plateau: no pipe saturated but all pipelining paths blocked by
//  measured hipcc spill behavior; shape/sync/balance levers at optimum.

typedef unsigned short ushort_t;
typedef __attribute__((ext_vector_type(8))) __bf16 bf16x8;
typedef __attribute__((ext_vector_type(4))) __bf16 bf16x4;
typedef __attribute__((ext_vector_type(4))) float floatx4;

__device__ __forceinline__ float bf2f(ushort_t u) {
  unsigned int x = ((unsigned int)u) << 16;
  return __builtin_bit_cast(float, x);
}
__device__ __forceinline__ ushort_t f2bf(float f) {
  unsigned int x = __builtin_bit_cast(unsigned int, f);
  unsigned int r = (x + 0x7FFFu + ((x >> 16) & 1u)) >> 16;
  return (ushort_t)r;
}

// ---------------- fused prelude: LN1 + all 4 weight repacks (independent work) ----------
__device__ __forceinline__ void transpose_w_body(const float* __restrict__ in,
                                                 ushort_t* __restrict__ out,
                                                 int R, int C, int bx, int by,
                                                 ushort_t* tl) {
  int tid = threadIdx.x;
  int c0 = bx * 64, r0 = by * 64;
  #pragma unroll
  for (int i = 0; i < 16; ++i) {
    int idx = tid + i * 256;
    int r = idx >> 6, c = idx & 63;
    tl[c * 65 + r] = f2bf(in[(size_t)(r0 + r) * C + c0 + c]);
  }
  __syncthreads();
  #pragma unroll
  for (int i = 0; i < 16; ++i) {
    int idx = tid + i * 256;
    int c = idx >> 6, r = idx & 63;
    out[(size_t)(c0 + c) * R + r0 + r] = tl[c * 65 + r];
  }
}

__global__ void __launch_bounds__(256) fused_pre(
    const float* __restrict__ x, const float* __restrict__ g1,
    const float* __restrict__ be1, ushort_t* __restrict__ hbuf,
    const float* __restrict__ wq, const float* __restrict__ wk,
    const float* __restrict__ wv, ushort_t* __restrict__ wqkvT,
    const float* __restrict__ w_proj, ushort_t* __restrict__ wprojT,
    const float* __restrict__ w_fc, ushort_t* __restrict__ wfcT,
    const float* __restrict__ w_cp, ushort_t* __restrict__ wcpT) {
  __shared__ ushort_t tl[64 * 65];
  __shared__ float ws1[4], ws2[4];
  int bid = blockIdx.x;
  int tid = threadIdx.x;
  if (bid < 8192) {
    const float* xr = x + (size_t)bid * 768;
    float v0 = xr[tid], v1 = xr[tid + 256], v2 = xr[tid + 512];
    float s = v0 + v1 + v2;
    float s2 = v0 * v0 + v1 * v1 + v2 * v2;
    #pragma unroll
    for (int off = 32; off; off >>= 1) {
      s += __shfl_xor(s, off, 64);
      s2 += __shfl_xor(s2, off, 64);
    }
    int w = tid >> 6;
    if ((tid & 63) == 0) { ws1[w] = s; ws2[w] = s2; }
    __syncthreads();
    float S = ws1[0] + ws1[1] + ws1[2] + ws1[3];
    float S2 = ws2[0] + ws2[1] + ws2[2] + ws2[3];
    float mean = S * (1.0f / 768.0f);
    float var = S2 * (1.0f / 768.0f) - mean * mean;
    float rstd = rsqrtf(var + 1e-5f);
    ushort_t* orow = hbuf + (size_t)bid * 768;
    orow[tid]       = f2bf((v0 - mean) * rstd * g1[tid]       + be1[tid]);
    orow[tid + 256] = f2bf((v1 - mean) * rstd * g1[tid + 256] + be1[tid + 256]);
    orow[tid + 512] = f2bf((v2 - mean) * rstd * g1[tid + 512] + be1[tid + 512]);
  } else if (bid < 8624) {
    int t = bid - 8192;
    int bx = t % 12, by = t / 12;
    int s = by / 12, h = by % 12;
    const float* w = ((s == 0) ? wq : (s == 1) ? wk : wv) + (size_t)h * 768 * 64;
    int d0 = bx * 64;
    #pragma unroll
    for (int i = 0; i < 16; ++i) {
      int idx = tid + i * 256;
      int r = idx >> 6, c = idx & 63;   // r: d offset, c: hd
      tl[c * 65 + r] = f2bf(w[(size_t)(d0 + r) * 64 + c]);
    }
    __syncthreads();
    ushort_t* ob = wqkvT + (size_t)(s * 768 + h * 64) * 768;
    #pragma unroll
    for (int i = 0; i < 16; ++i) {
      int idx = tid + i * 256;
      int c = idx >> 6, r = idx & 63;   // c: hd, r: d offset
      ob[(size_t)c * 768 + d0 + r] = tl[c * 65 + r];
    }
  } else if (bid < 8768) {
    int t = bid - 8624;
    transpose_w_body(w_proj, wprojT, 768, 768, t % 12, t / 12, tl);
  } else if (bid < 9344) {
    int t = bid - 8768;
    transpose_w_body(w_fc, wfcT, 768, 3072, t % 48, t / 48, tl);
  } else {
    int t = bid - 9344;
    transpose_w_body(w_cp, wcpT, 3072, 768, t % 12, t / 12, tl);
  }
}

// ---------------- layernorm: fp32 row [768] -> bf16 row (LN2) ----------------
__global__ void __launch_bounds__(256) ln_kernel(const float* __restrict__ x,
                                                 const float* __restrict__ g,
                                                 const float* __restrict__ b,
                                                 ushort_t* __restrict__ out) {
  int row = blockIdx.x;
  int tid = threadIdx.x;
  const float* xr = x + (size_t)row * 768;
  float v0 = xr[tid], v1 = xr[tid + 256], v2 = xr[tid + 512];
  float s = v0 + v1 + v2;
  float s2 = v0 * v0 + v1 * v1 + v2 * v2;
  #pragma unroll
  for (int off = 32; off; off >>= 1) {
    s += __shfl_xor(s, off, 64);
    s2 += __shfl_xor(s2, off, 64);
  }
  __shared__ float ws1[4], ws2[4];
  int w = tid >> 6;
  if ((tid & 63) == 0) { ws1[w] = s; ws2[w] = s2; }
  __syncthreads();
  float S = ws1[0] + ws1[1] + ws1[2] + ws1[3];
  float S2 = ws2[0] + ws2[1] + ws2[2] + ws2[3];
  float mean = S * (1.0f / 768.0f);
  float var = S2 * (1.0f / 768.0f) - mean * mean;
  float rstd = rsqrtf(var + 1e-5f);
  ushort_t* orow = out + (size_t)row * 768;
  orow[tid]       = f2bf((v0 - mean) * rstd * g[tid]       + b[tid]);
  orow[tid + 256] = f2bf((v1 - mean) * rstd * g[tid + 256] + b[tid + 256]);
  orow[tid + 512] = f2bf((v2 - mean) * rstd * g[tid + 512] + b[tid + 512]);
}

// ---------------- 64x128 MFMA GEMM (R20 proven: 2-barrier, named-scalar staging) --------
enum { EPI_QKV = 0, EPI_RES = 1, EPI_FC = 2 };

template <int EPI>
__global__ void __launch_bounds__(256) gemm64t(
    const ushort_t* __restrict__ A, const ushort_t* __restrict__ Bt,
    int M, int N, int K,
    const float* __restrict__ b0, const float* __restrict__ b1, const float* __restrict__ b2,
    const float* __restrict__ resid,
    ushort_t* __restrict__ ob0, ushort_t* __restrict__ ob1, ushort_t* __restrict__ ob2,
    float* __restrict__ of) {
  __shared__ __align__(16) ushort_t la[64 * 64];
  __shared__ __align__(16) ushort_t lb[128 * 64];
  int tid = threadIdx.x;
  int lane = tid & 63;
  int w = tid >> 6;
  int wr = w >> 1, wc = w & 1;
  int lm = lane & 15, q = lane >> 4;
  int m0 = blockIdx.x * 64, n0 = blockIdx.y * 128;

  const ushort_t* Ab = A + (size_t)m0 * K;
  const ushort_t* Bb = Bt + (size_t)n0 * K;

  floatx4 acc[2][4];
  #pragma unroll
  for (int i = 0; i < 2; ++i)
    #pragma unroll
    for (int j = 0; j < 4; ++j) acc[i][j] = (floatx4){0.f, 0.f, 0.f, 0.f};

  int srow = tid >> 3;            // 0..31
  int sch  = tid & 7;             // chunk 0..7
  for (int k0 = 0; k0 < K; k0 += 64) {
    uint4 av0 = *reinterpret_cast<const uint4*>(Ab + (size_t)srow * K + k0 + sch * 8);
    uint4 av1 = *reinterpret_cast<const uint4*>(Ab + (size_t)(srow + 32) * K + k0 + sch * 8);
    uint4 bv0 = *reinterpret_cast<const uint4*>(Bb + (size_t)srow * K + k0 + sch * 8);
    uint4 bv1 = *reinterpret_cast<const uint4*>(Bb + (size_t)(srow + 32) * K + k0 + sch * 8);
    uint4 bv2 = *reinterpret_cast<const uint4*>(Bb + (size_t)(srow + 64) * K + k0 + sch * 8);
    uint4 bv3 = *reinterpret_cast<const uint4*>(Bb + (size_t)(srow + 96) * K + k0 + sch * 8);
    __syncthreads();   // previous tile's LDS reads all consumed
    *reinterpret_cast<uint4*>(&la[srow * 64 + ((sch ^ (srow & 7)) << 3)]) = av0;
    *reinterpret_cast<uint4*>(&la[(srow + 32) * 64 + ((sch ^ (srow & 7)) << 3)]) = av1;
    *reinterpret_cast<uint4*>(&lb[srow * 64 + ((sch ^ (srow & 7)) << 3)]) = bv0;
    *reinterpret_cast<uint4*>(&lb[(srow + 32) * 64 + ((sch ^ (srow & 7)) << 3)]) = bv1;
    *reinterpret_cast<uint4*>(&lb[(srow + 64) * 64 + ((sch ^ (srow & 7)) << 3)]) = bv2;
    *reinterpret_cast<uint4*>(&lb[(srow + 96) * 64 + ((sch ^ (srow & 7)) << 3)]) = bv3;
    __syncthreads();
    #pragma unroll
    for (int kk = 0; kk < 64; kk += 32) {
      int ch = (kk >> 3) + q;
      bf16x8 af[2], bfr[4];
      #pragma unroll
      for (int i = 0; i < 2; ++i) {
        int ra = wr * 32 + i * 16 + lm;
        af[i]  = *reinterpret_cast<const bf16x8*>(&la[ra * 64 + ((ch ^ (ra & 7)) << 3)]);
      }
      #pragma unroll
      for (int j = 0; j < 4; ++j) {
        int rb = wc * 64 + j * 16 + lm;
        bfr[j] = *reinterpret_cast<const bf16x8*>(&lb[rb * 64 + ((ch ^ (rb & 7)) << 3)]);
      }
      #pragma unroll
      for (int i = 0; i < 2; ++i)
        #pragma unroll
        for (int j = 0; j < 4; ++j)
          acc[i][j] = __builtin_amdgcn_mfma_f32_16x16x32_bf16(af[i], bfr[j], acc[i][j], 0, 0, 0);
    }
  }

  // epilogue; C/D layout: row(m)=quad*4+reg, col(n)=lane&15  [verified m89/m91]
  #pragma unroll
  for (int i = 0; i < 2; ++i) {
    #pragma unroll
    for (int j = 0; j < 4; ++j) {
      #pragma unroll
      for (int r = 0; r < 4; ++r) {
        float vacc = acc[i][j][r];
        int mm = m0 + wr * 32 + i * 16 + q * 4 + r;
        int nn = n0 + wc * 64 + j * 16 + lm;
        if constexpr (EPI == EPI_QKV) {
          int sel = nn / 768;            // 0:q 1:k 2:v (uniform per block: 128 | 768)
          int nq = nn - sel * 768;       // h*64+hd
          const float* bp = (sel == 0) ? b0 : (sel == 1) ? b1 : b2;
          ushort_t* dst = (sel == 0) ? ob0 : (sel == 1) ? ob1 : ob2;
          int bh = (mm >> 10) * 12 + (nq >> 6);
          size_t o = (size_t)bh * 65536 + (size_t)(mm & 1023) * 64 + (nq & 63);
          dst[o] = f2bf(vacc + bp[nq]);
        } else if constexpr (EPI == EPI_RES) {
          size_t o = (size_t)mm * 768 + nn;
          of[o] = vacc + b0[nn] + resid[o];
        } else {  // EPI_FC: gelu(acc+bias) -> bf16 [M,3072]
          float u = vacc + b0[nn];
          float inner = 0.7978845608028654f * (u + 0.044715f * u * u * u);
          // exact tanh-gelu: 0.5*u*(1+tanh(inner)) = u - u/(exp(2*inner)+1)
          float e = __builtin_amdgcn_exp2f(inner * 2.885390081777927f);  // 2*log2(e)
          float gl = u - u / (e + 1.0f);   // e=inf -> u; e=0 -> 0 (NaN-safe)
          ob0[(size_t)mm * 3072 + nn] = f2bf(gl);
        }
      }
    }
  }
}

// ---------------- V transpose: [bh][1024][64] -> [bh][64][1024] (bf16) ----------------
__global__ void __launch_bounds__(256) transpose_v(const ushort_t* __restrict__ vb,
                                                   ushort_t* __restrict__ vt) {
  __shared__ ushort_t tl[64 * 72];
  int kt = blockIdx.x, bh = blockIdx.y;
  size_t base = (size_t)bh * 65536;
  int tid = threadIdx.x;
  #pragma unroll
  for (int i = 0; i < 2; ++i) {
    int r = (tid >> 3) + i * 32;     // local key row
    int cb = (tid & 7) * 8;          // dim chunk
    *reinterpret_cast<uint4*>(&tl[r * 72 + cb]) =
        *reinterpret_cast<const uint4*>(vb + base + (size_t)(kt * 64 + r) * 64 + cb);
  }
  __syncthreads();
  #pragma unroll
  for (int i = 0; i < 2; ++i) {
    int dim = (tid >> 3) + i * 32;
    int kb8 = (tid & 7) * 8;
    ushort_t tmp[8];
    #pragma unroll
    for (int j = 0; j < 8; ++j) tmp[j] = tl[(kb8 + j) * 72 + dim];
    *reinterpret_cast<uint4*>(vt + base + (size_t)dim * 1024 + kt * 64 + kb8) =
        *reinterpret_cast<uint4*>(tmp);
  }
}

// ---------------- MFMA flash attention (paired q-tiles, XOR-swizzled LDS) ----------------
__global__ void __launch_bounds__(256) attn_mfma(const ushort_t* __restrict__ qb,
                                                 const ushort_t* __restrict__ kb,
                                                 const ushort_t* __restrict__ vtb,
                                                 ushort_t* __restrict__ yb) {
  __shared__ __align__(16) ushort_t kl[64 * 64];   // K tile [key][dim], swizzled
  __shared__ __align__(16) ushort_t vtl[64 * 64];  // V^T tile [dim][key], swizzled
  int p = blockIdx.x;                              // 0..7
  int bh = blockIdx.y;
  int tid = threadIdx.x, lane = tid & 63, w = tid >> 6;
  int col = lane & 15, quad = lane >> 4;
  size_t base = (size_t)bh * 65536;
  int b = bh / 12, h = bh - b * 12;
  const float sscale = 0.125f * 1.4426950408889634f;  // 1/sqrt(64) * log2(e)

  for (int phase = 0; phase < 2; ++phase) {
    int qt = (phase == 0) ? (15 - p) : p;          // heavy first
    int qw0 = qt * 64 + w * 16;                    // wave's first query
    int qg = qw0 + col;

    bf16x8 qf0 = *reinterpret_cast<const bf16x8*>(qb + base + (size_t)(qw0 + col) * 64 + quad * 8);
    bf16x8 qf1 = *reinterpret_cast<const bf16x8*>(qb + base + (size_t)(qw0 + col) * 64 + 32 + quad * 8);

    floatx4 O[4];
    #pragma unroll
    for (int ss = 0; ss < 4; ++ss) O[ss] = (floatx4){0.f, 0.f, 0.f, 0.f};
    float m = -INFINITY, l = 0.f;

    for (int kt0 = 0; kt0 <= qt * 64; kt0 += 64) {
      __syncthreads();   // previous tile's (or phase's) LDS reads all consumed
      {
        int r0 = tid >> 3;           // 0..31
        int cb = tid & 7;            // chunk 0..7
        int sw = (cb ^ (r0 & 7)) << 3;
        *reinterpret_cast<uint4*>(&kl[r0 * 64 + sw]) =
            *reinterpret_cast<const uint4*>(kb + base + (size_t)(kt0 + r0) * 64 + cb * 8);
        *reinterpret_cast<uint4*>(&vtl[r0 * 64 + sw]) =
            *reinterpret_cast<const uint4*>(vtb + base + (size_t)r0 * 1024 + kt0 + cb * 8);
        int r1 = r0 + 32;            // (r1&7)==(r0&7), same swizzle slot
        *reinterpret_cast<uint4*>(&kl[r1 * 64 + sw]) =
            *reinterpret_cast<const uint4*>(kb + base + (size_t)(kt0 + r1) * 64 + cb * 8);
        *reinterpret_cast<uint4*>(&vtl[r1 * 64 + sw]) =
            *reinterpret_cast<const uint4*>(vtb + base + (size_t)r1 * 1024 + kt0 + cb * 8);
      }
      __syncthreads();
      int nk = qw0 + 16 - kt0;           // keys this wave needs in this tile
      if (nk > 64) nk = 64;
      int ng = (nk + 31) >> 5;           // 32-key groups
      for (int g = 0; g < ng; ++g) {
        int ksA = kt0 + g * 32;
        int ksB = ksA + 16;
        int rowA = g * 32 + col;          // key row for subtile A
        int rxa = rowA & 7;               // == (rowA+16)&7
        int sa = rowA * 64;
        int sb = sa + 16 * 64;
        bf16x8 kfA0 = *reinterpret_cast<const bf16x8*>(&kl[sa + ((quad ^ rxa) << 3)]);
        bf16x8 kfA1 = *reinterpret_cast<const bf16x8*>(&kl[sa + (((4 + quad) ^ rxa) << 3)]);
        bf16x8 kfB0 = *reinterpret_cast<const bf16x8*>(&kl[sb + ((quad ^ rxa) << 3)]);
        bf16x8 kfB1 = *reinterpret_cast<const bf16x8*>(&kl[sb + (((4 + quad) ^ rxa) << 3)]);
        floatx4 saA = (floatx4){0.f, 0.f, 0.f, 0.f};
        floatx4 saB = (floatx4){0.f, 0.f, 0.f, 0.f};
        __builtin_amdgcn_s_setprio(1);
        saA = __builtin_amdgcn_mfma_f32_16x16x32_bf16(kfA0, qf0, saA, 0, 0, 0);
        saA = __builtin_amdgcn_mfma_f32_16x16x32_bf16(kfA1, qf1, saA, 0, 0, 0);
        saB = __builtin_amdgcn_mfma_f32_16x16x32_bf16(kfB0, qf0, saB, 0, 0, 0);
        saB = __builtin_amdgcn_mfma_f32_16x16x32_bf16(kfB1, qf1, saB, 0, 0, 0);
        __builtin_amdgcn_s_setprio(0);
        float s0 = saA[0] * sscale, s1 = saA[1] * sscale;
        float s2 = saA[2] * sscale, s3 = saA[3] * sscale;
        float s4 = saB[0] * sscale, s5 = saB[1] * sscale;
        float s6 = saB[2] * sscale, s7 = saB[3] * sscale;
        if (ksA + 15 > qw0) {   // wave-uniform: subtile A touches/crosses diagonal
          int keyb = ksA + quad * 4;
          if (keyb + 0 > qg) s0 = -3.0e38f;
          if (keyb + 1 > qg) s1 = -3.0e38f;
          if (keyb + 2 > qg) s2 = -3.0e38f;
          if (keyb + 3 > qg) s3 = -3.0e38f;
        }
        if (ksB + 15 > qw0) {   // wave-uniform: subtile B (also handles odd tail)
          int keyb = ksB + quad * 4;
          if (keyb + 0 > qg) s4 = -3.0e38f;
          if (keyb + 1 > qg) s5 = -3.0e38f;
          if (keyb + 2 > qg) s6 = -3.0e38f;
          if (keyb + 3 > qg) s7 = -3.0e38f;
        }
        float mloc = fmaxf(fmaxf(fmaxf(s0, s1), fmaxf(s2, s3)),
                           fmaxf(fmaxf(s4, s5), fmaxf(s6, s7)));
        mloc = fmaxf(mloc, __shfl_xor(mloc, 16, 64));
        mloc = fmaxf(mloc, __shfl_xor(mloc, 32, 64));
        float mnew = fmaxf(m, mloc);
        float c = __builtin_amdgcn_exp2f(m - mnew);
        float p0 = __builtin_amdgcn_exp2f(s0 - mnew);
        float p1 = __builtin_amdgcn_exp2f(s1 - mnew);
        float p2 = __builtin_amdgcn_exp2f(s2 - mnew);
        float p3 = __builtin_amdgcn_exp2f(s3 - mnew);
        float p4 = __builtin_amdgcn_exp2f(s4 - mnew);
        float p5 = __builtin_amdgcn_exp2f(s5 - mnew);
        float p6 = __builtin_amdgcn_exp2f(s6 - mnew);
        float p7 = __builtin_amdgcn_exp2f(s7 - mnew);
        float ll = ((p0 + p1) + (p2 + p3)) + ((p4 + p5) + (p6 + p7));
        ll += __shfl_xor(ll, 16, 64);
        ll += __shfl_xor(ll, 32, 64);
        l = l * c + ll;
        m = mnew;
        float c0 = __shfl(c, quad * 4 + 0, 64);
        float c1 = __shfl(c, quad * 4 + 1, 64);
        float c2 = __shfl(c, quad * 4 + 2, 64);
        float c3 = __shfl(c, quad * 4 + 3, 64);
        bf16x8 pf = {(__bf16)p0, (__bf16)p1, (__bf16)p2, (__bf16)p3,
                     (__bf16)p4, (__bf16)p5, (__bf16)p6, (__bf16)p7};
        __builtin_amdgcn_s_setprio(1);
        #pragma unroll
        for (int ss = 0; ss < 4; ++ss) {
          O[ss][0] *= c0; O[ss][1] *= c1; O[ss][2] *= c2; O[ss][3] *= c3;
          int vd = ss * 16 + col;
          int vbase = vd * 64;
          int vx = vd & 7;
          int ca = g * 4 + (quad >> 1);
          int ia = (quad & 1) * 4;
          bf16x4 va = *reinterpret_cast<const bf16x4*>(&vtl[vbase + ((ca ^ vx) << 3) + ia]);
          bf16x4 vb = *reinterpret_cast<const bf16x4*>(&vtl[vbase + (((ca + 2) ^ vx) << 3) + ia]);
          bf16x8 vf = {va[0], va[1], va[2], va[3], vb[0], vb[1], vb[2], vb[3]};
          O[ss] = __builtin_amdgcn_mfma_f32_16x16x32_bf16(pf, vf, O[ss], 0, 0, 0);
        }
        __builtin_amdgcn_s_setprio(0);
      }
    }

    float linv = 1.0f / l;
    float l0 = __shfl(linv, quad * 4 + 0, 64);
    float l1 = __shfl(linv, quad * 4 + 1, 64);
    float l2 = __shfl(linv, quad * 4 + 2, 64);
    float l3 = __shfl(linv, quad * 4 + 3, 64);
    #pragma unroll
    for (int ss = 0; ss < 4; ++ss) {
      float lr[4] = {l0, l1, l2, l3};
      #pragma unroll
      for (int r = 0; r < 4; ++r) {
        int t = qw0 + quad * 4 + r;
        yb[((size_t)(b * 1024 + t)) * 768 + h * 64 + ss * 16 + col] = f2bf(O[ss][r] * lr[r]);
      }
    }
  }
}

// ---------------- launch ----------------
extern "C" void kernel_launch(void* const* d_in, const int* in_sizes, int n_in,
                              void* d_out, int out_size, void* d_ws, size_t ws_size,
                              hipStream_t stream) {
  const float* x      = (const float*)d_in[0];
  const float* wq     = (const float*)d_in[1];
  const float* bq     = (const float*)d_in[2];
  const float* wk     = (const float*)d_in[3];
  const float* bk     = (const float*)d_in[4];
  const float* wv     = (const float*)d_in[5];
  const float* bv     = (const float*)d_in[6];
  const float* w_proj = (const float*)d_in[7];
  const float* b_proj = (const float*)d_in[8];
  const float* g1     = (const float*)d_in[9];
  const float* be1    = (const float*)d_in[10];
  const float* g2     = (const float*)d_in[11];
  const float* be2    = (const float*)d_in[12];
  const float* w_fc   = (const float*)d_in[13];
  const float* b_fc   = (const float*)d_in[14];
  const float* w_cp   = (const float*)d_in[15];
  const float* b_cp   = (const float*)d_in[16];
  float* out = (float*)d_out;

  char* ws = (char*)d_ws;
  size_t off = 0;
  auto alloc = [&](size_t bytes) -> char* {
    char* p = ws + off;
    off += (bytes + 255) & ~(size_t)255;
    return p;
  };
  const size_t MD = 8192ull * 768;  // B*T*D elements
  ushort_t* wqkvT  = (ushort_t*)alloc(2304ull * 768 * 2);   // [N=2304][K=768]
  ushort_t* wprojT = (ushort_t*)alloc(768ull * 768 * 2);    // [N=768][K=768]
  ushort_t* wfcT   = (ushort_t*)alloc(3072ull * 768 * 2);   // [N=3072][K=768]
  ushort_t* wcpT   = (ushort_t*)alloc(768ull * 3072 * 2);   // [N=768][K=3072]
  ushort_t* hbuf   = (ushort_t*)alloc(MD * 2);
  ushort_t* qbuf   = (ushort_t*)alloc(MD * 2);
  ushort_t* kbuf   = (ushort_t*)alloc(MD * 2);
  ushort_t* vbuf   = (ushort_t*)alloc(MD * 2);
  ushort_t* ybuf   = (ushort_t*)alloc(MD * 2);
  float*    x1     = (float*)alloc(MD * 4);
  ushort_t* h2buf  = (ushort_t*)alloc(MD * 2);
  // aliases (lifetimes disjoint): vtbuf reuses hbuf (dead after QKV GEMM);
  // fcbuf reuses qbuf..ybuf (48 MB exactly, dead after proj GEMM)
  ushort_t* vtbuf  = hbuf;
  ushort_t* fcbuf  = qbuf;

  // fused prelude: LN1 + all 4 weight repacks (independent; one dispatch)
  fused_pre<<<9920, 256, 0, stream>>>(x, g1, be1, hbuf, wq, wk, wv, wqkvT,
                                      w_proj, wprojT, w_fc, wfcT, w_cp, wcpT);
  // QKV projection (fused q|k|v, scatter to [B,H,T,HD] bf16): 64x128 tiles
  gemm64t<EPI_QKV><<<dim3(128, 18), 256, 0, stream>>>(
      hbuf, wqkvT, 8192, 2304, 768, bq, bk, bv, nullptr, qbuf, kbuf, vbuf, nullptr);
  // V -> V^T  (hbuf dead, reused as vtbuf)
  transpose_v<<<dim3(16, 96), 256, 0, stream>>>(vbuf, vtbuf);
  // causal MFMA flash attention (paired q-tiles: grid (8, 96))
  attn_mfma<<<dim3(8, 96), 256, 0, stream>>>(qbuf, kbuf, vtbuf, ybuf);
  // out-proj + bias + residual(x) -> x1 fp32: 64x128 tiles, 768 blocks
  gemm64t<EPI_RES><<<dim3(128, 6), 256, 0, stream>>>(
      ybuf, wprojT, 8192, 768, 768, b_proj, nullptr, nullptr, x,
      nullptr, nullptr, nullptr, x1);
  // LN2
  ln_kernel<<<8192, 256, 0, stream>>>(x1, g2, be2, h2buf);
  // FC + gelu -> bf16 (fcbuf aliases qbuf..ybuf, all dead now): 64x128 tiles
  gemm64t<EPI_FC><<<dim3(128, 24), 256, 0, stream>>>(
      h2buf, wfcT, 8192, 3072, 768, b_fc, nullptr, nullptr, nullptr,
      fcbuf, nullptr, nullptr, nullptr);
  // CP + bias + residual(x1) -> out fp32: 64x128 tiles, 768 blocks
  gemm64t<EPI_RES><<<dim3(128, 6), 256, 0, stream>>>(
      fcbuf, wcpT, 8192, 768, 3072, b_cp, nullptr, nullptr, x1,
      nullptr, nullptr, nullptr, out);
}